// Round 3
// 1933.364 us; speedup vs baseline: 1.0394x; 1.0394x over previous
//
#include <hip/hip_runtime.h>

// NeuroVoltron v7: v6 with the compile error fixed. v5/v6 both died on
// __builtin_nontemporal_store(float4*, ...) — HIP's float4 is a class type the
// builtin rejects. Store through a clang ext_vector type instead (lowers to the
// same global_store_dwordx4 nt). Protocol and math identical to v6:
//  - v4's proven counter-barrier (monotone, R*(t+1) target, parity zx buffer)
//  - arrive moved INTO P4 (tid464 RELEASE fetch_add after its z-publish)
//  - gh (whh GEMV) overlaps tid0's poll window
//  - msgs nt-stores in P4 (drain coalesces with z-publish drain)
//  - own-room z stays in LDS; refresh loads only 11 remote rooms

constexpr int R  = 12;
constexpr int L  = 32;
constexpr int M  = 16;
constexpr int HH = 32;
constexpr int HF = 64;
constexpr int E  = 132;
constexpr int G3 = 96;      // 3*HH
constexpr float DT = 0.1f;

constexpr int G  = 4;       // batch elements per block
constexpr int BS = 512;
constexpr int BARSTRIDE = 64;   // uints per barrier counter (256 B line)

typedef float f4v __attribute__((ext_vector_type(4)));   // nt-store-compatible

__device__ __forceinline__ float sigmoidf(float x) {
    return 1.0f / (1.0f + __expf(-x));
}
__device__ __forceinline__ float fma4(float4 a, float4 x, float acc) {
    acc = fmaf(a.x, x.x, acc);
    acc = fmaf(a.y, x.y, acc);
    acc = fmaf(a.z, x.z, acc);
    return fmaf(a.w, x.w, acc);
}

__global__ __launch_bounds__(BS) void nv_main(
    const float* __restrict__ z0,     const float* __restrict__ h0,
    const float* __restrict__ mean_w, const float* __restrict__ mean_b,
    const float* __restrict__ add_w,
    const float* __restrict__ gsw,    const float* __restrict__ gsb,
    const float* __restrict__ gcw,
    const float* __restrict__ lw,     const float* __restrict__ lb,
    const float* __restrict__ ow_w,   const float* __restrict__ ob,
    const float* __restrict__ wih,    const float* __restrict__ whh,
    const float* __restrict__ bih,    const float* __restrict__ bhh,
    const int* __restrict__ src_idx,  const int* __restrict__ tgt_idx,
    const int* __restrict__ n_steps_p,
    float* __restrict__ zx, unsigned int* __restrict__ bar,
    float* __restrict__ out, int B)
{
    const int r   = blockIdx.x;       // room
    const int grp = blockIdx.y;       // batch group
    const int tid = threadIdx.x;
    const int T   = n_steps_p[0];
    const int b0  = grp * G;

    // output layout: z_traj (B,T,R,L) | h_f (B,R,HH) | msgs (B,T,E,M)
    float* __restrict__ out_z    = out;
    float* __restrict__ out_hf   = out + (size_t)B * T * R * L;
    float* __restrict__ out_msgs = out_hf + (size_t)B * R * HH;

    __shared__ __align__(16) float wadd_s[11 * L * M];   // [(e*4+c)*32+l] packed f4 over m
    __shared__ __align__(16) float zS[G * R * L];        // [g][room][l]
    __shared__ __align__(16) float hSS[G * HH];          // [g][hh] (own room)
    __shared__ __align__(16) float meanS[G * 11 * M];    // [g][e_local*16+m]
    __shared__ __align__(16) float incS[G * L];
    __shared__ __align__(16) float gateS[G * L];
    __shared__ __align__(16) float shSS[G * HF];
    __shared__ __align__(16) float giSS[G * G3];
    __shared__ __align__(16) float ghSS[G * G3];
    __shared__ int edgeE[11], edgeSrc[11];

    // ---- edge tables for this room ----
    if (tid == 0) {
        int c = 0;
        for (int e = 0; e < E; ++e)
            if (tgt_idx[e] == r) { edgeE[c] = e; edgeSrc[c] = src_idx[e]; ++c; }
    }
    __syncthreads();

    // ---- one-time: load my weight row into registers (uniform wbuf union) ----
    float4 wbuf[16];
#pragma unroll
    for (int k = 0; k < 16; ++k) wbuf[k] = make_float4(0.f, 0.f, 0.f, 0.f);
    float bias = 0.f;
    const float4* wsA = nullptr;
    const float4* wsB = nullptr;
    if (tid < 176) {                       // mean rows: (e_local, m)
        const int el = tid >> 4, m = tid & 15;
        const int row = edgeE[el] * M + m;
        wsA = (const float4*)(mean_w + (size_t)row * L);
        bias = mean_b[row];
    } else if (tid < 272) {                // gh rows (whh)
        const int j = tid - 176, row = r * G3 + j;
        wsA = (const float4*)(whh + (size_t)row * HH);
        bias = bhh[row];
    } else if (tid < 304) {                // gate rows (gsw || gcw)
        const int j = tid - 272, row = r * L + j;
        wsA = (const float4*)(gsw + (size_t)row * L);
        wsB = (const float4*)(gcw + (size_t)row * L);
        bias = gsb[row];
    } else if (tid < 368) {                // silu rows (lw, 64 wide)
        const int j = tid - 304, row = r * HF + j;
        wsA = (const float4*)(lw + (size_t)row * 2 * L);
        wsB = wsA + 8;
        bias = lb[row];
    } else if (tid < 464) {                // gi rows (wih)
        const int j = tid - 368, row = r * G3 + j;
        wsA = (const float4*)(wih + (size_t)row * L);
        bias = bih[row];
    } else if (tid < 496) {                // ow rows (64 wide)
        const int j = tid - 464, row = r * L + j;
        wsA = (const float4*)(ow_w + (size_t)row * HF);
        wsB = wsA + 8;
        bias = ob[row];
    }
    if (wsA) {
#pragma unroll
        for (int k = 0; k < 8; ++k) wbuf[k] = wsA[k];
    }
    if (wsB) {
#pragma unroll
        for (int k = 0; k < 8; ++k) wbuf[8 + k] = wsB[k];
    }

    // ---- one-time: add_w slice -> LDS (transposed, f4-packed over m) ----
    for (int i = tid; i < 11 * L * M; i += BS) {
        const int e = i >> 9, rem = i & 511, l = rem >> 4, m = rem & 15;
        wadd_s[((e * 4 + (m >> 2)) * 32 + l) * 4 + (m & 3)] =
            add_w[((size_t)edgeE[e] * L + l) * M + m];
    }
    // ---- state init ----
    for (int i = tid; i < G * R * L; i += BS) {
        const int g = i / (R * L), rl = i - g * (R * L);
        zS[i] = z0[(size_t)(b0 + g) * R * L + rl];
    }
    for (int i = tid; i < G * HH; i += BS) {
        const int g = i >> 5, hh = i & 31;
        hSS[i] = h0[(size_t)(b0 + g) * R * HH + r * HH + hh];
    }
    __syncthreads();

    unsigned int* __restrict__ mybar = &bar[(size_t)grp * BARSTRIDE];

    auto do_gh = [&]() {
        const int j = tid - 176;
#pragma unroll
        for (int g = 0; g < G; ++g) {
            const float4* hp = (const float4*)(hSS + g * HH);
            float a = bias;
#pragma unroll
            for (int c = 0; c < 8; ++c) a = fma4(wbuf[c], hp[c], a);
            ghSS[g * G3 + j] = a;
        }
    };

    for (int t = 0; t < T; ++t) {
        // ---- P1: mean (T0-175) | gh at t==0 only (T176-271) ----
        if (tid < 176) {
            const int el = tid >> 4, m = tid & 15;
            const int sr = edgeSrc[el];
#pragma unroll
            for (int g = 0; g < G; ++g) {
                const float4* zp = (const float4*)(zS + g * (R * L) + sr * L);
                float a = bias;
#pragma unroll
                for (int c = 0; c < 8; ++c) a = fma4(wbuf[c], zp[c], a);
                meanS[g * 176 + el * 16 + m] = a;
            }
        } else if (t == 0 && tid >= 176 && tid < 272) {
            do_gh();        // steady-state gh runs in the poll window below
        }
        __syncthreads();

        // ---- P2: inc (T0-127: (g,l)) from LDS wadd + meanS ----
        if (tid < 128) {
            const int g = tid >> 5, l = tid & 31;
            const float4* mp = (const float4*)(meanS + g * 176);
            const float4* wp = (const float4*)wadd_s;
            float a = 0.f;
#pragma unroll
            for (int e = 0; e < 11; ++e)
#pragma unroll
                for (int c = 0; c < 4; ++c)
                    a = fma4(wp[(e * 4 + c) * 32 + l], mp[e * 4 + c], a);
            incS[g * L + l] = a;
        }
        __syncthreads();

        // ---- P3: gate (272-303) | silu (304-367) | gi (368-463) ----
        if (tid >= 272 && tid < 304) {
            const int j = tid - 272;
#pragma unroll
            for (int g = 0; g < G; ++g) {
                const float4* zp = (const float4*)(zS + g * (R * L) + r * L);
                const float4* ip = (const float4*)(incS + g * L);
                float a = bias;
#pragma unroll
                for (int c = 0; c < 8; ++c) {
                    a = fma4(wbuf[c], zp[c], a);
                    a = fma4(wbuf[8 + c], ip[c], a);
                }
                gateS[g * L + j] = sigmoidf(a);
            }
        } else if (tid >= 304 && tid < 368) {
            const int j = tid - 304;
#pragma unroll
            for (int g = 0; g < G; ++g) {
                const float4* zp = (const float4*)(zS + g * (R * L) + r * L);
                const float4* ip = (const float4*)(incS + g * L);
                float a = bias;
#pragma unroll
                for (int c = 0; c < 8; ++c) {
                    a = fma4(wbuf[c], zp[c], a);
                    a = fma4(wbuf[8 + c], ip[c], a);
                }
                shSS[g * HF + j] = a * sigmoidf(a);
            }
        } else if (tid >= 368 && tid < 464) {
            const int j = tid - 368;
#pragma unroll
            for (int g = 0; g < G; ++g) {
                const float4* ip = (const float4*)(incS + g * L);
                float a = bias;
#pragma unroll
                for (int c = 0; c < 8; ++c) a = fma4(wbuf[c], ip[c], a);
                giSS[g * G3 + j] = a;
            }
        }
        __syncthreads();

        // ---- P4: z-out + publish + ARRIVE (464-495) | GRU (176-303) | msgs (0-175) ----
        const int p = t & 1;
        float* __restrict__ zxp = zx + (size_t)p * B * (R * L);
        if (tid >= 464 && tid < 496) {
            const int j = tid - 464;
#pragma unroll
            for (int g = 0; g < G; ++g) {
                const float4* sp = (const float4*)(shSS + g * HF);
                float a = bias;
#pragma unroll
                for (int c = 0; c < 16; ++c) a = fma4(wbuf[c], sp[c], a);
                const float target = tanhf(a);
                const float zv = zS[g * (R * L) + r * L + j];
                const float znew = zv + DT * gateS[g * L + j] * (target - zv);
                zS[g * (R * L) + r * L + j] = znew;   // own-room z stays in LDS
                __hip_atomic_store(&zxp[(size_t)(b0 + g) * (R * L) + r * L + j], znew,
                                   __ATOMIC_RELAXED, __HIP_MEMORY_SCOPE_AGENT);
                __builtin_nontemporal_store(
                    znew, &out_z[((size_t)(b0 + g) * T + t) * (R * L) + r * L + j]);
            }
            // Early arrive: RELEASE drains this wave's z-publish stores, then
            // the RMW overlaps the P4 sync and other blocks' P4 compute.
            if (tid == 464 && t + 1 < T)
                __hip_atomic_fetch_add(mybar, 1u, __ATOMIC_RELEASE,
                                       __HIP_MEMORY_SCOPE_AGENT);
        } else if (tid >= 176 && tid < 304) {
            const int i = tid - 176;
            const int g = i >> 5, hh = i & 31;
            const float ir  = giSS[g * G3 + hh];
            const float iz  = giSS[g * G3 + HH + hh];
            const float inn = giSS[g * G3 + 2 * HH + hh];
            const float hr  = ghSS[g * G3 + hh];
            const float hz  = ghSS[g * G3 + HH + hh];
            const float hnv = ghSS[g * G3 + 2 * HH + hh];
            const float reset = sigmoidf(ir + hr);
            const float upd   = sigmoidf(iz + hz);
            const float nw    = tanhf(inn + reset * hnv);
            hSS[g * HH + hh] = (1.0f - upd) * nw + upd * hSS[g * HH + hh];
        } else if (tid < 176) {
            // msgs nt-stores here: drain coalesces with the z-publish drain at
            // this phase's single sync instead of taxing the P1 sync.
            const int g = tid / 44, i = tid - g * 44;     // i in 0..43 (f4 over 11*M)
            const int el = i >> 2, m4 = i & 3;
            const f4v v = *(const f4v*)(meanS + g * 176 + i * 4);
            __builtin_nontemporal_store(
                v, (f4v*)&out_msgs[((size_t)(b0 + g) * T + t) * (E * M)
                                   + edgeE[el] * 16 + m4 * 4]);
        }
        __syncthreads();

        if (t + 1 < T) {
            // ---- poll window: tid0 spins | gh for next step (176-271) ----
            if (tid == 0) {
                const unsigned int tgt = (unsigned int)R * (unsigned int)(t + 1);
                while (__hip_atomic_load(mybar, __ATOMIC_RELAXED,
                                         __HIP_MEMORY_SCOPE_AGENT) < tgt)
                    __builtin_amdgcn_s_sleep(1);
            } else if (tid >= 176 && tid < 272) {
                do_gh();
            }
            __syncthreads();

            // ---- refresh the 11 remote rooms' z (352 threads, 4 floats each) ----
            if (tid < 352) {
                const int team = tid >> 5, lane = tid & 31;
                const int s = team + (team >= r ? 1 : 0);     // remote room
                const int g = lane >> 3, l4 = lane & 7;
                const float* sp = zxp + (size_t)(b0 + g) * (R * L) + s * L + l4 * 4;
                float4 v;
                v.x = __hip_atomic_load(sp + 0, __ATOMIC_RELAXED, __HIP_MEMORY_SCOPE_AGENT);
                v.y = __hip_atomic_load(sp + 1, __ATOMIC_RELAXED, __HIP_MEMORY_SCOPE_AGENT);
                v.z = __hip_atomic_load(sp + 2, __ATOMIC_RELAXED, __HIP_MEMORY_SCOPE_AGENT);
                v.w = __hip_atomic_load(sp + 3, __ATOMIC_RELAXED, __HIP_MEMORY_SCOPE_AGENT);
                ((float4*)zS)[g * (R * L / 4) + s * (L / 4) + l4] = v;
            }
            __syncthreads();
        }
    }

    // ---- final h ----
    for (int i = tid; i < G * HH; i += BS) {
        const int g = i >> 5, hh = i & 31;
        __builtin_nontemporal_store(
            hSS[i], &out_hf[(size_t)(b0 + g) * R * HH + r * HH + hh]);
    }
}

extern "C" void kernel_launch(void* const* d_in, const int* in_sizes, int n_in,
                              void* d_out, int out_size, void* d_ws, size_t ws_size,
                              hipStream_t stream) {
    const float* z0     = (const float*)d_in[0];
    const float* h0     = (const float*)d_in[1];
    const float* mean_w = (const float*)d_in[2];
    const float* mean_b = (const float*)d_in[3];
    const float* add_w  = (const float*)d_in[4];
    const float* gsw    = (const float*)d_in[5];
    const float* gsb    = (const float*)d_in[6];
    const float* gcw    = (const float*)d_in[7];
    const float* lw     = (const float*)d_in[8];
    const float* lb     = (const float*)d_in[9];
    const float* ow_w   = (const float*)d_in[10];
    const float* ob     = (const float*)d_in[11];
    const float* wih    = (const float*)d_in[12];
    const float* whh    = (const float*)d_in[13];
    const float* bih    = (const float*)d_in[14];
    const float* bhh    = (const float*)d_in[15];
    const int* src_idx  = (const int*)d_in[16];
    const int* tgt_idx  = (const int*)d_in[17];
    const int* n_steps  = (const int*)d_in[18];

    const int B  = in_sizes[0] / (R * L);
    const int NG = B / G;   // batch groups

    float* wsf = (float*)d_ws;
    float* zx  = wsf;                                        // 2*B*R*L floats
    unsigned int* bar = (unsigned int*)(wsf + 2 * (size_t)B * R * L); // NG*64 uints

    (void)hipMemsetAsync(bar, 0, (size_t)NG * BARSTRIDE * sizeof(unsigned int), stream);

    nv_main<<<dim3(R, NG), dim3(BS), 0, stream>>>(
        z0, h0, mean_w, mean_b, add_w, gsw, gsb, gcw, lw, lb, ow_w, ob,
        wih, whh, bih, bhh, src_idx, tgt_idx, n_steps,
        zx, bar, (float*)d_out, B);
}